// Round 8
// baseline (629.162 us; speedup 1.0000x reference)
//
#include <hip/hip_runtime.h>
#include <hip/hip_cooperative_groups.h>

// Segment-mean, single cooperative dispatch, 4 phases split by grid.sync():
//   P0 zero counts/ovf  P1 scatter_slots  P2 paired gather  P3 ovf fixup.
// Slots layout: slots[id*16+k] = row (k from atomicAdd on counts).
// Gather: 16 lanes/segment-pair, up to 8 predicated src loads in flight.

#define SLOTS   16
#define OVF_CAP 8192

typedef float f32x4 __attribute__((ext_vector_type(4)));
typedef int   i32x4 __attribute__((ext_vector_type(4)));

namespace cg = cooperative_groups;

__global__ void __launch_bounds__(256, 2) fused_pool(
    const int* __restrict__ ids, const float* __restrict__ src,
    int* __restrict__ counts, int* __restrict__ slots, int* __restrict__ ovf,
    float* __restrict__ out, int n, int m)
{
    cg::grid_group grid = cg::this_grid();
    const int tid = blockIdx.x * blockDim.x + threadIdx.x;
    const int nthreads = gridDim.x * blockDim.x;

    // ---- P0: zero counts + ovf counter (slots needs no zeroing) ----
    {
        i32x4* c4 = reinterpret_cast<i32x4*>(counts);
        const int m4 = m >> 2;
        for (int i = tid; i < m4; i += nthreads) c4[i] = (i32x4)(0);
        if (tid == 0) ovf[0] = 0;
    }
    grid.sync();

    // ---- P1: scatter rows into per-segment slots ----
    {
        const int n4 = n >> 2;
        for (int i = tid; i < n4; i += nthreads) {
            const i32x4 v = __builtin_nontemporal_load(
                reinterpret_cast<const i32x4*>(ids) + i);
            const int r0 = i << 2;
            #pragma unroll
            for (int j = 0; j < 4; ++j) {
                const int id = v[j];
                const int k  = atomicAdd(&counts[id], 1);
                if (k < SLOTS) {
                    slots[id * SLOTS + k] = r0 + j;
                } else {
                    int p = atomicAdd(ovf, 1);
                    if (p < OVF_CAP) { ovf[1 + 2 * p] = r0 + j; ovf[2 + 2 * p] = id; }
                }
            }
        }
    }
    grid.sync();

    // ---- P2: paired gather (2 segments per 16-lane group, MLP=8) ----
    {
        const int  pairs = m >> 1;
        const long tasks = (long)pairs * 16;
        const f32x4* s4 = reinterpret_cast<const f32x4*>(src);
        for (long t = tid; t < tasks; t += nthreads) {
            const int p = (int)(t >> 4);
            const int q = (int)(t & 15);
            const int sA = 2 * p, sB = 2 * p + 1;
            const int2 c2 = *reinterpret_cast<const int2*>(counts + sA);
            const int cA = c2.x, cB = c2.y;
            const int lA = cA < SLOTS ? cA : SLOTS;
            const int lB = cB < SLOTS ? cB : SLOTS;
            const long bA = (long)sA * SLOTS, bB = (long)sB * SLOTS;
            f32x4 aA = (f32x4)(0.f), aB = (f32x4)(0.f);
            const int lmax = lA > lB ? lA : lB;
            for (int kk = 0; kk < lmax; kk += 4) {
                const i32x4 xA = *reinterpret_cast<const i32x4*>(slots + bA + kk);
                const i32x4 xB = *reinterpret_cast<const i32x4*>(slots + bB + kk);
                const int rA = lA - kk, rB = lB - kk;
                f32x4 vA0 = (f32x4)(0.f), vA1 = vA0, vA2 = vA0, vA3 = vA0;
                f32x4 vB0 = vA0, vB1 = vA0, vB2 = vA0, vB3 = vA0;
                if (rA > 0) vA0 = __builtin_nontemporal_load(s4 + ((long)xA[0] * 16 + q));
                if (rB > 0) vB0 = __builtin_nontemporal_load(s4 + ((long)xB[0] * 16 + q));
                if (rA > 1) vA1 = __builtin_nontemporal_load(s4 + ((long)xA[1] * 16 + q));
                if (rB > 1) vB1 = __builtin_nontemporal_load(s4 + ((long)xB[1] * 16 + q));
                if (rA > 2) vA2 = __builtin_nontemporal_load(s4 + ((long)xA[2] * 16 + q));
                if (rB > 2) vB2 = __builtin_nontemporal_load(s4 + ((long)xB[2] * 16 + q));
                if (rA > 3) vA3 = __builtin_nontemporal_load(s4 + ((long)xA[3] * 16 + q));
                if (rB > 3) vB3 = __builtin_nontemporal_load(s4 + ((long)xB[3] * 16 + q));
                aA += (vA0 + vA1) + (vA2 + vA3);
                aB += (vB0 + vB1) + (vB2 + vB3);
            }
            aA *= 1.0f / (float)(cA > 1 ? cA : 1);
            aB *= 1.0f / (float)(cB > 1 ? cB : 1);
            __builtin_nontemporal_store(aA, reinterpret_cast<f32x4*>(out) + ((long)sA * 16 + q));
            __builtin_nontemporal_store(aB, reinterpret_cast<f32x4*>(out) + ((long)sB * 16 + q));
        }
    }
    grid.sync();

    // ---- P3: overflow fixup (empty in practice) ----
    {
        int novf = ovf[0];
        if (novf > OVF_CAP) novf = OVF_CAP;
        const int total = novf * 16;
        for (int t = tid; t < total; t += nthreads) {
            const int e = t >> 4, q = t & 15;
            const int row = ovf[1 + 2 * e], id = ovf[2 + 2 * e];
            const float rcp = 1.0f / (float)counts[id];
            const float4 v = reinterpret_cast<const float4*>(src)[(long)row * 16 + q];
            float* o = out + (long)id * 64 + q * 4;
            unsafeAtomicAdd(o + 0, v.x * rcp);
            unsafeAtomicAdd(o + 1, v.y * rcp);
            unsafeAtomicAdd(o + 2, v.z * rcp);
            unsafeAtomicAdd(o + 3, v.w * rcp);
        }
    }
}

extern "C" void kernel_launch(void* const* d_in, const int* in_sizes, int n_in,
                              void* d_out, int out_size, void* d_ws, size_t ws_size,
                              hipStream_t stream) {
    const int* ids_c = (const int*)d_in[0];
    const float* src_c = (const float*)d_in[1];
    float* out = (float*)d_out;

    int n = in_sizes[0];                   // N = 2097152 (divisible by 4)
    int m = out_size / 64;                 // M = 524288 (even)

    // Workspace (ints): counts[m] | ovf[1+2*OVF_CAP] | slots[m*SLOTS]
    int* counts = (int*)d_ws;
    int* ovf    = counts + m;
    int* slots  = ovf + (1 + 2 * OVF_CAP);

    // Co-resident grid sizing (pure host query — capture-safe, deterministic).
    int blocksPerCU = 0;
    (void)hipOccupancyMaxActiveBlocksPerMultiprocessor(
        &blocksPerCU, (const void*)fused_pool, 256, 0);
    if (blocksPerCU < 1) blocksPerCU = 1;
    int gridBlocks = blocksPerCU * 256;
    if (gridBlocks > 2048) gridBlocks = 2048;

    const int* ids = ids_c; const float* src = src_c;
    void* args[] = {(void*)&ids, (void*)&src, (void*)&counts, (void*)&slots,
                    (void*)&ovf, (void*)&out, (void*)&n, (void*)&m};
    (void)hipLaunchCooperativeKernel((void*)fused_pool, dim3(gridBlocks), dim3(256),
                                     args, 0, stream);
}

// Round 9
// 304.479 us; speedup vs baseline: 2.0664x; 2.0664x over previous
//
#include <hip/hip_runtime.h>

// Segment-mean, 4 dispatches:
//   0. zero_counts: counts=0, ovf[0]=0 (one tiny kernel, replaces 2 memsets)
//   1. scatter_slots: atomicAdd(&counts[id],1) -> count + slot k;
//      row stored at slots[id*16+k]; rows past 16 (P ~1.5e-7/seg) -> ovf list.
//   2. gather_mean: 16 lanes per segment-PAIR. Slot-quads for rows 0..7 of
//      both segments (2 cache lines) are hoisted to issue IN PARALLEL with
//      the counts load (epoch collapse 3->2); up to 8 predicated src loads
//      in flight; out written once, coalesced nontemporal.
//   3. ovf_fix: empty in practice; unconditional correctness.

#define SLOTS   16
#define OVF_CAP 8192

typedef float f32x4 __attribute__((ext_vector_type(4)));
typedef int   i32x4 __attribute__((ext_vector_type(4)));

__global__ void zero_counts(int* __restrict__ counts, int* __restrict__ ovf, int m4) {
    const int stride = gridDim.x * blockDim.x;
    i32x4* c4 = reinterpret_cast<i32x4*>(counts);
    for (int i = blockIdx.x * blockDim.x + threadIdx.x; i < m4; i += stride)
        c4[i] = (i32x4)(0);
    if (blockIdx.x == 0 && threadIdx.x == 0) ovf[0] = 0;
}

__global__ void scatter_slots(const int* __restrict__ ids,
                              int* __restrict__ counts,
                              int* __restrict__ slots,
                              int* __restrict__ ovf,   // [0]=n_ovf, then (row,id) pairs
                              int n4) {
    const int i = blockIdx.x * blockDim.x + threadIdx.x;
    if (i >= n4) return;
    const i32x4 v = __builtin_nontemporal_load(reinterpret_cast<const i32x4*>(ids) + i);
    const int r0 = i << 2;
    #pragma unroll
    for (int j = 0; j < 4; ++j) {
        const int id = v[j];
        const int k  = atomicAdd(&counts[id], 1);
        if (k < SLOTS) {
            slots[id * SLOTS + k] = r0 + j;
        } else {
            int p = atomicAdd(ovf, 1);
            if (p < OVF_CAP) { ovf[1 + 2 * p] = r0 + j; ovf[2 + 2 * p] = id; }
        }
    }
}

__global__ void gather_mean(const float* __restrict__ src,
                            const int* __restrict__ slots,
                            const int* __restrict__ counts,
                            float* __restrict__ out, int m) {
    const int t = blockIdx.x * blockDim.x + threadIdx.x;
    const int p = t >> 4;                         // segment PAIR index
    const int q = t & 15;                         // float4 slot: 4 channels
    const int sA = 2 * p, sB = 2 * p + 1;
    if (sB >= m) return;                          // m even -> exact
    const long bA = (long)sA * SLOTS, bB = (long)sB * SLOTS;
    // All five loads below are address-independent -> issued concurrently.
    // Slot values past the (not yet known) count are stale garbage but are
    // never used as addresses (src loads predicated on counts).
    const i32x4 xA0 = *reinterpret_cast<const i32x4*>(slots + bA);
    const i32x4 xB0 = *reinterpret_cast<const i32x4*>(slots + bB);
    const i32x4 xA1 = *reinterpret_cast<const i32x4*>(slots + bA + 4);
    const i32x4 xB1 = *reinterpret_cast<const i32x4*>(slots + bB + 4);
    const int2  c2  = *reinterpret_cast<const int2*>(counts + sA);
    const int cA = c2.x, cB = c2.y;
    const int lA = cA < SLOTS ? cA : SLOTS;
    const int lB = cB < SLOTS ? cB : SLOTS;
    const f32x4* s4 = reinterpret_cast<const f32x4*>(src);
    f32x4 aA = (f32x4)(0.f), aB = (f32x4)(0.f);

    {   // rows 0..3 of each segment: up to 8 predicated loads in flight
        f32x4 vA0 = (f32x4)(0.f), vA1 = vA0, vA2 = vA0, vA3 = vA0;
        f32x4 vB0 = vA0, vB1 = vA0, vB2 = vA0, vB3 = vA0;
        if (lA > 0) vA0 = __builtin_nontemporal_load(s4 + ((long)xA0[0] * 16 + q));
        if (lB > 0) vB0 = __builtin_nontemporal_load(s4 + ((long)xB0[0] * 16 + q));
        if (lA > 1) vA1 = __builtin_nontemporal_load(s4 + ((long)xA0[1] * 16 + q));
        if (lB > 1) vB1 = __builtin_nontemporal_load(s4 + ((long)xB0[1] * 16 + q));
        if (lA > 2) vA2 = __builtin_nontemporal_load(s4 + ((long)xA0[2] * 16 + q));
        if (lB > 2) vB2 = __builtin_nontemporal_load(s4 + ((long)xB0[2] * 16 + q));
        if (lA > 3) vA3 = __builtin_nontemporal_load(s4 + ((long)xA0[3] * 16 + q));
        if (lB > 3) vB3 = __builtin_nontemporal_load(s4 + ((long)xB0[3] * 16 + q));
        aA += (vA0 + vA1) + (vA2 + vA3);
        aB += (vB0 + vB1) + (vB2 + vB3);
    }
    if ((lA > 4) || (lB > 4)) {   // rows 4..7 (~60% of pairs), slots pre-loaded
        const int rA = lA - 4, rB = lB - 4;
        f32x4 vA0 = (f32x4)(0.f), vA1 = vA0, vA2 = vA0, vA3 = vA0;
        f32x4 vB0 = vA0, vB1 = vA0, vB2 = vA0, vB3 = vA0;
        if (rA > 0) vA0 = __builtin_nontemporal_load(s4 + ((long)xA1[0] * 16 + q));
        if (rB > 0) vB0 = __builtin_nontemporal_load(s4 + ((long)xB1[0] * 16 + q));
        if (rA > 1) vA1 = __builtin_nontemporal_load(s4 + ((long)xA1[1] * 16 + q));
        if (rB > 1) vB1 = __builtin_nontemporal_load(s4 + ((long)xB1[1] * 16 + q));
        if (rA > 2) vA2 = __builtin_nontemporal_load(s4 + ((long)xA1[2] * 16 + q));
        if (rB > 2) vB2 = __builtin_nontemporal_load(s4 + ((long)xB1[2] * 16 + q));
        if (rA > 3) vA3 = __builtin_nontemporal_load(s4 + ((long)xA1[3] * 16 + q));
        if (rB > 3) vB3 = __builtin_nontemporal_load(s4 + ((long)xB1[3] * 16 + q));
        aA += (vA0 + vA1) + (vA2 + vA3);
        aB += (vB0 + vB1) + (vB2 + vB3);
        // rows 8..15 (P(cnt>8) ~2% per segment)
        const int lmax = lA > lB ? lA : lB;
        for (int kk = 8; kk < lmax; kk += 4) {
            const i32x4 yA = *reinterpret_cast<const i32x4*>(slots + bA + kk);
            const i32x4 yB = *reinterpret_cast<const i32x4*>(slots + bB + kk);
            const int tA = lA - kk, tB = lB - kk;
            f32x4 wA0 = (f32x4)(0.f), wA1 = wA0, wA2 = wA0, wA3 = wA0;
            f32x4 wB0 = wA0, wB1 = wA0, wB2 = wA0, wB3 = wA0;
            if (tA > 0) wA0 = __builtin_nontemporal_load(s4 + ((long)yA[0] * 16 + q));
            if (tB > 0) wB0 = __builtin_nontemporal_load(s4 + ((long)yB[0] * 16 + q));
            if (tA > 1) wA1 = __builtin_nontemporal_load(s4 + ((long)yA[1] * 16 + q));
            if (tB > 1) wB1 = __builtin_nontemporal_load(s4 + ((long)yB[1] * 16 + q));
            if (tA > 2) wA2 = __builtin_nontemporal_load(s4 + ((long)yA[2] * 16 + q));
            if (tB > 2) wB2 = __builtin_nontemporal_load(s4 + ((long)yB[2] * 16 + q));
            if (tA > 3) wA3 = __builtin_nontemporal_load(s4 + ((long)yA[3] * 16 + q));
            if (tB > 3) wB3 = __builtin_nontemporal_load(s4 + ((long)yB[3] * 16 + q));
            aA += (wA0 + wA1) + (wA2 + wA3);
            aB += (wB0 + wB1) + (wB2 + wB3);
        }
    }
    aA *= 1.0f / (float)(cA > 1 ? cA : 1);
    aB *= 1.0f / (float)(cB > 1 ? cB : 1);
    __builtin_nontemporal_store(aA, reinterpret_cast<f32x4*>(out) + ((long)sA * 16 + q));
    __builtin_nontemporal_store(aB, reinterpret_cast<f32x4*>(out) + ((long)sB * 16 + q));
}

__global__ void ovf_fix(const float* __restrict__ src,
                        const int* __restrict__ counts,
                        const int* __restrict__ ovf,
                        float* __restrict__ out) {
    int novf = ovf[0];
    if (novf > OVF_CAP) novf = OVF_CAP;
    const int total  = novf * 16;
    const int stride = gridDim.x * blockDim.x;
    for (int t = blockIdx.x * blockDim.x + threadIdx.x; t < total; t += stride) {
        const int e = t >> 4, q = t & 15;
        const int row = ovf[1 + 2 * e], id = ovf[2 + 2 * e];
        const float rcp = 1.0f / (float)counts[id];
        const float4 v = reinterpret_cast<const float4*>(src)[(long)row * 16 + q];
        float* o = out + (long)id * 64 + q * 4;
        unsafeAtomicAdd(o + 0, v.x * rcp);
        unsafeAtomicAdd(o + 1, v.y * rcp);
        unsafeAtomicAdd(o + 2, v.z * rcp);
        unsafeAtomicAdd(o + 3, v.w * rcp);
    }
}

extern "C" void kernel_launch(void* const* d_in, const int* in_sizes, int n_in,
                              void* d_out, int out_size, void* d_ws, size_t ws_size,
                              hipStream_t stream) {
    const int*   ids = (const int*)d_in[0];
    const float* src = (const float*)d_in[1];
    float*       out = (float*)d_out;

    const int n = in_sizes[0];                   // N = 2097152 (divisible by 4)
    const int m = out_size / 64;                 // M = 524288 (even)

    // Workspace (ints): counts[m] | ovf[1+2*OVF_CAP] | slots[m*SLOTS]
    int* counts = (int*)d_ws;
    int* ovf    = counts + m;
    int* slots  = ovf + (1 + 2 * OVF_CAP);

    zero_counts<<<256, 256, 0, stream>>>(counts, ovf, m >> 2);
    const int n4 = n >> 2;
    scatter_slots<<<(n4 + 255) / 256, 256, 0, stream>>>(ids, counts, slots, ovf, n4);
    const int pairs = m / 2;
    gather_mean<<<(pairs * 16 + 255) / 256, 256, 0, stream>>>(src, slots, counts, out, m);
    ovf_fix<<<64, 256, 0, stream>>>(src, counts, ovf, out);
}